// Round 7
// baseline (316.976 us; speedup 1.0000x reference)
//
#include <hip/hip_runtime.h>

#define NB 4
#define P 1024
#define ITERS 50
#define WPB 16              // iteration workgroups per batch
#define THREADS 1024
#define WAVES 16
#define ITERWGS (NB * WPB)  // 64 iteration WGs
#define NGRID 256           // + 192 copy WGs fused in the same launch
#define K_COEF (-14.426950408889634f)   // -log2(e)/eps, eps=0.1
#define INV_KCOEF (-0.06931471805599453f) // 1/K_COEF
#define DELTA 1e-8f
#define SCALE 274877906944.0f           // 2^38 fixed-point scale
#define M56 0x00FFFFFFFFFFFFFFull
#define CNT_ONE (1ull << 56)

typedef unsigned long long u64;
typedef unsigned int u32;

// ws layout: z[NB][ITERS][P << zshift] u64 : (arrivals<<56) | fixed-point sum
// zshift in [0,3] chosen host-side from ws_size (3 => 64B per column, no
// false sharing of memory-side atomic lines).

__global__ void sink_zero(u64* z, float* out, int nwords) {
    int t = blockIdx.x * 1024 + threadIdx.x;
    if (t < nwords) z[t] = 0ull;
    if (t < NB) out[t] = 0.0f;
}

__global__ __launch_bounds__(THREADS, 1)
void sink_main(const float* __restrict__ mu, const float* __restrict__ nu,
               const float* __restrict__ C, float* __restrict__ out,
               u64* __restrict__ z, int zshift) {
    const int bid = blockIdx.x;
    const int tid = threadIdx.x;

    float* out_pi = out + 4;
    float* out_C  = out + 4 + (size_t)NB * P * P;

    if (bid >= ITERWGS) {
        // ---- copy WGs: stream C -> out_C while iter WGs run (latency-bound)
        const size_t nvec = (size_t)NB * P * P / 4;           // 1M float4
        const size_t nthr = (size_t)(NGRID - ITERWGS) * THREADS;
        size_t i = (size_t)(bid - ITERWGS) * THREADS + tid;
        const float4* src = reinterpret_cast<const float4*>(C);
        float4* dst = reinterpret_cast<float4*>(out_C);
        for (; i < nvec; i += nthr) dst[i] = src[i];
        return;
    }

    const int n   = bid >> 4;          // batch
    const int w   = bid & 15;          // wg within batch
    const int wq  = tid >> 6;          // wave 0..15
    const int l   = tid & 63;          // lane

    u64* zb = z + ((size_t)n * ITERS * P << zshift);
    const float* Cb = C + (size_t)n * P * P;
    const int base = w * 64 + wq * 4;  // this wave's first row

    float Kr[4][16], muv[4], b_r[16], a_own[4];

    // Kr[q][k] = K[base+q][l+64k]  (each load: 64 lanes x 4B = 256B coalesced)
    #pragma unroll
    for (int q = 0; q < 4; ++q) {
        const int r = base + q;
        #pragma unroll
        for (int k = 0; k < 16; ++k)
            Kr[q][k] = exp2f(K_COEF * Cb[(size_t)r * P + l + 64 * k]);
        muv[q] = mu[n * P + r] + DELTA;
    }
    const float nuv_s = (nu[n * P + tid] + DELTA) * SCALE;  // own column = tid

    __shared__ float bs[P];            // 4KB  : broadcast b
    __shared__ float zs[WAVES][P];     // 64KB : per-wave column partials

    #pragma unroll
    for (int k = 0; k < 16; ++k) b_r[k] = 1.0f;   // v=0 -> b=1

    for (int t = 0; t < ITERS; ++t) {
        // a_i = (mu_i+d) / sum_j K_ij b_j   (own rows, never published)
        #pragma unroll
        for (int q = 0; q < 4; ++q) {
            float y = 0.f;
            #pragma unroll
            for (int k = 0; k < 16; ++k) y += Kr[q][k] * b_r[k];
            #pragma unroll
            for (int off = 32; off > 0; off >>= 1) y += __shfl_xor(y, off, 64);
            a_own[q] = muv[q] / y;
        }
        // per-wave column partials
        #pragma unroll
        for (int k = 0; k < 16; ++k)
            zs[wq][l + 64 * k] = Kr[0][k] * a_own[0] + Kr[1][k] * a_own[1]
                               + Kr[2][k] * a_own[2] + Kr[3][k] * a_own[3];
        __syncthreads();
        // WG reduce -> ONE tagged fixed-point RMW per column (padded line)
        float red = 0.f;
        #pragma unroll
        for (int g = 0; g < WAVES; ++g) red += zs[g][tid];
        u64* myz = zb + (((size_t)t * P + tid) << zshift);
        const u64 own = CNT_ONE + (u64)(red * SCALE);
        u64 v = __hip_atomic_fetch_add(myz, own, __ATOMIC_RELAXED,
                                       __HIP_MEMORY_SCOPE_AGENT) + own;
        while ((v >> 56) != (u64)WPB) {
            __builtin_amdgcn_s_sleep(1);
            v = __hip_atomic_load(myz, __ATOMIC_RELAXED,
                                  __HIP_MEMORY_SCOPE_AGENT);
        }
        bs[tid] = nuv_s / (float)(v & M56);   // b_j = nu_j / z_j
        __syncthreads();
        #pragma unroll
        for (int k = 0; k < 16; ++k) b_r[k] = bs[l + 64 * k];
        // no further barrier: poll-pass at t+1 transitively implies all WGs
        // passed this iteration's barriers (fetch_add is program-ordered
        // after the zs reads and b_r reads it guards).
    }

    // fused epilogue: pi = a_i K_ij b_j ; cost = sum pi*C (C reconstructed
    // from Kr: c = log2(K)/K_COEF, err ~1e-6 << 2e-2 threshold). out_C was
    // copied by the overlap WGs; only pi is written here.
    float costp = 0.f;
    #pragma unroll
    for (int q = 0; q < 4; ++q) {
        const int r = base + q;
        const size_t rowoff = (size_t)n * P * P + (size_t)r * P;
        #pragma unroll
        for (int k = 0; k < 16; ++k) {
            const int j = l + 64 * k;
            const float c = __log2f(Kr[q][k]) * INV_KCOEF;
            const float p = a_own[q] * Kr[q][k] * b_r[k];
            out_pi[rowoff + j] = p;
            costp += p * c;
        }
    }
    #pragma unroll
    for (int off = 32; off > 0; off >>= 1) costp += __shfl_xor(costp, off, 64);
    __syncthreads();               // bs free for reuse
    if (l == 0) bs[wq] = costp;
    __syncthreads();
    if (tid == 0) {
        float s = 0.f;
        #pragma unroll
        for (int g = 0; g < WAVES; ++g) s += bs[g];
        atomicAdd(&out[n], s);
    }
}

extern "C" void kernel_launch(void* const* d_in, const int* in_sizes, int n_in,
                              void* d_out, int out_size, void* d_ws, size_t ws_size,
                              hipStream_t stream) {
    const float* mu = (const float*)d_in[0];
    const float* nu = (const float*)d_in[1];
    const float* C  = (const float*)d_in[2];
    float* out = (float*)d_out;
    u64* zws = (u64*)d_ws;

    // pick the largest per-column padding that fits the workspace
    const size_t base_bytes = (size_t)NB * ITERS * P * sizeof(u64);  // 1.6 MB
    int zshift = 0;
    while (zshift < 3 && (base_bytes << (zshift + 1)) <= ws_size) ++zshift;

    const int nwords = (NB * ITERS * P) << zshift;
    sink_zero<<<(nwords + 1023) / 1024, 1024, 0, stream>>>(zws, out, nwords);
    sink_main<<<NGRID, THREADS, 0, stream>>>(mu, nu, C, out, zws, zshift);
}